// Round 5
// baseline (3919.376 us; speedup 1.0000x reference)
//
#include <hip/hip_runtime.h>
#include <stdint.h>

typedef unsigned short u16;
typedef unsigned long long u64;
typedef __attribute__((ext_vector_type(8))) short short8;
typedef __attribute__((ext_vector_type(4))) float f32x4;
typedef __attribute__((ext_vector_type(4))) unsigned int u32x4;

#define B_ 32
#define S_ 512
#define H_ 1024
#define NBLK 64   // recurrence workgroups (<=256 CUs -> co-resident, spin barrier safe)

// ---- workspace layout (bytes) — footprint IDENTICAL to round-2/4 ----
// flags[64] (one int per WG, 4B stride) occupy the old 256B bar region.
// dtype flag relocated into the 256B pad after the h double-buffer.
static const size_t OFF_BAR  = 0;                         // flags[64] ints
static const size_t OFF_HBF  = 256;                       // h double buffer: 2*32*1024*2
static const size_t OFF_DFLG = OFF_HBF + 131072;          // dtype flag (in old pad)
static const size_t OFF_BIAS = OFF_HBF + 131072 + 256;    // fp32[4096]
static const size_t OFF_UT   = OFF_BIAS + 16384;          // U^T bf16 [4096][1024]
static const size_t OFF_VP   = OFF_UT + 8388608;          // V fragment-permuted bf16
static const size_t OFF_XU   = OFF_VP + 8388608;          // xu bf16 [512][32][4096]
static const size_t WS_NEED  = OFF_XU + (size_t)S_ * B_ * 4 * H_ * 2;

__device__ inline float bf2f(u16 u) {
    union { unsigned i; float f; } v; v.i = ((unsigned)u) << 16; return v.f;
}
__device__ inline u16 f2bf(float f) {
    union { float f; unsigned i; } v; v.f = f;
    unsigned r = v.i + 0x7fffu + ((v.i >> 16) & 1u);   // RNE
    return (u16)(r >> 16);
}
__device__ inline float sigm(float x) { return 1.0f / (1.0f + __expf(-x)); }
__device__ inline float tanh_(float x) {
    x = fminf(fmaxf(x, -30.0f), 30.0f);
    float e = __expf(-2.0f * x);
    return (1.0f - e) / (1.0f + e);
}
// NaN-proof clamp: fmaxf/fminf drop a NaN operand -> result always finite.
__device__ inline float zclamp(float x) { return fminf(fmaxf(x, -60.0f), 60.0f); }

// dual-dtype element read -> bf16 bits
__device__ inline u16 rd_bf(const void* p, size_t idx, int isbf) {
    return isbf ? ((const u16*)p)[idx] : f2bf(((const float*)p)[idx]);
}
__device__ inline float rd_f(const void* p, size_t idx, int isbf) {
    return isbf ? bf2f(((const u16*)p)[idx]) : ((const float*)p)[idx];
}

// system-scope 16B load: bypass (possibly stale) per-CU L1 / per-XCD L2,
// served by the coherent memory-side Infinity Cache. Issues WITHOUT an
// implicit waitcnt -> caller batches N loads then waits ONCE.
__device__ inline short8 llc_load16(const u16* p) {
    u32x4 r;
    asm volatile("global_load_dwordx4 %0, %1, off sc0 sc1"
                 : "=&v"(r) : "v"(p));
    union { u32x4 u; short8 s; } cv; cv.u = r; return cv.s;
}

// ---------------- dtype probe ----------------
__global__ void prep_probe(const void* x, int* flag) {
    if (blockIdx.x == 0 && threadIdx.x == 0) {
        const u16* p = (const u16*)x;
        int bfish = 0;
        for (int i = 0; i < 512; i += 2) {
            int e = (p[i] >> 7) & 0xFF;
            if (e >= 118 && e <= 131) ++bfish;
        }
        flag[0] = (bfish >= 128) ? 1 : 0;   // 1 = bf16 buffers, 0 = fp32 buffers
    }
}

// ---------------- prep kernels ----------------

__global__ void prep_misc(const void* b0, const void* b1, const void* b2, const void* b3,
                          float* __restrict__ bias, const void* h0,
                          u16* __restrict__ hbf, const int* __restrict__ flag) {
    const int isbf = flag[0];
    int i = blockIdx.x * 256 + threadIdx.x;
    if (i < 4096) {
        int g = i >> 10, n = i & 1023;
        const void* bp = (g == 0) ? b0 : (g == 1) ? b1 : (g == 2) ? b2 : b3;
        bias[i] = rd_f(bp, n, isbf);
    }
    int j = i - 4096;
    if (j >= 0 && j < B_ * H_) hbf[j] = rd_bf(h0, j, isbf);
}

// Ut[(g*1024+n)*1024 + k] = U_g[k*1024 + n]
__global__ void prep_ut(const void* u0, const void* u1, const void* u2, const void* u3,
                        u16* __restrict__ Ut, const int* __restrict__ flag) {
    const int isbf = flag[0];
    int idx = blockIdx.x * 256 + threadIdx.x;          // [4][128][1024]
    int g  = idx >> 17;
    int k8 = (idx >> 10) & 127;
    int n  = idx & 1023;
    const void* Ug = (g == 0) ? u0 : (g == 1) ? u1 : (g == 2) ? u2 : u3;
    int k0 = k8 * 8;
    union { u16 a[8]; short8 v; } t;
#pragma unroll
    for (int j = 0; j < 8; ++j) t.a[j] = rd_bf(Ug, (size_t)(k0 + j) * 1024 + n, isbf);
    *(short8*)(Ut + ((size_t)(g * 1024 + n) * 1024 + k0)) = t.v;
}

// Vp[((g*64+nb)*32+ks)*64+lane][8] = V_g[k][n], n=nb*16+(lane&15), k=ks*32+(lane>>4)*8+j
__global__ void prep_vp(const void* v0, const void* v1, const void* v2, const void* v3,
                        u16* __restrict__ Vp, const int* __restrict__ flag) {
    const int isbf = flag[0];
    int idx = blockIdx.x * 256 + threadIdx.x;          // [4][64][32][64]
    int lane = idx & 63;
    int ks = (idx >> 6) & 31;
    int nb = (idx >> 11) & 63;
    int g  = idx >> 17;
    const void* Vg = (g == 0) ? v0 : (g == 1) ? v1 : (g == 2) ? v2 : v3;
    int n  = nb * 16 + (lane & 15);
    int kb = ks * 32 + (lane >> 4) * 8;
    union { u16 a[8]; short8 v; } t;
#pragma unroll
    for (int j = 0; j < 8; ++j) t.a[j] = rd_bf(Vg, (size_t)(kb + j) * 1024 + n, isbf);
    *(short8*)(Vp + (size_t)idx * 8) = t.v;
}

// ---------------- phase 1: xu = x @ U + b  (bf16 out, [s][b][4096]) ----------------

__global__ __launch_bounds__(256) void gemm_xu(
    const void* __restrict__ xv, const u16* __restrict__ Ut,
    const float* __restrict__ bias, u16* __restrict__ xu,
    const int* __restrict__ flag) {
    const int isbf = flag[0];
    const int bx = blockIdx.x;
    const int m0 = (bx & 127) * 128;
    const int n0 = (bx >> 7) * 128;
    const int tid = threadIdx.x;
    const int w = tid >> 6, lane = tid & 63;
    const int lm = lane & 15, q = lane >> 4;
    const int r4 = lane >> 2, c4 = lane & 3;

    __shared__ __attribute__((aligned(16))) u16 As[128 * 32];
    __shared__ __attribute__((aligned(16))) u16 Bs[128 * 32];

    const int mb = (w >> 1) * 64, nbL = (w & 1) * 64;
    f32x4 acc[4][4] = {};

    for (int k0 = 0; k0 < 1024; k0 += 32) {
        __syncthreads();
#pragma unroll
        for (int i2 = 0; i2 < 2; ++i2) {
            const int i = w * 2 + i2;
            const size_t aoff = (size_t)(m0 + i * 16 + r4) * 1024 + k0 + c4 * 8;
            if (isbf) {
                const u16* ga = (const u16*)xv + aoff;
                __builtin_amdgcn_global_load_lds((const __attribute__((address_space(1))) void*)ga,
                                                 (__attribute__((address_space(3))) void*)(As + i * 512),
                                                 16, 0, 0);
            } else {
                const float* ga = (const float*)xv + aoff;
                f32x4 f0 = *(const f32x4*)ga;
                f32x4 f1 = *(const f32x4*)(ga + 4);
                union { u16 a[8]; short8 v; } t;
#pragma unroll
                for (int j = 0; j < 4; ++j) { t.a[j] = f2bf(f0[j]); t.a[4 + j] = f2bf(f1[j]); }
                *(short8*)(As + i * 512 + lane * 8) = t.v;
            }
            const u16* gb = Ut + (size_t)(n0 + i * 16 + r4) * 1024 + k0 + c4 * 8;
            __builtin_amdgcn_global_load_lds((const __attribute__((address_space(1))) void*)gb,
                                             (__attribute__((address_space(3))) void*)(Bs + i * 512),
                                             16, 0, 0);
        }
        __syncthreads();

        short8 af[4], bf[4];
#pragma unroll
        for (int mt = 0; mt < 4; ++mt)
            af[mt] = *(const short8*)(As + (mb + mt * 16 + lm) * 32 + q * 8);
#pragma unroll
        for (int nt = 0; nt < 4; ++nt)
            bf[nt] = *(const short8*)(Bs + (nbL + nt * 16 + lm) * 32 + q * 8);
#pragma unroll
        for (int mt = 0; mt < 4; ++mt)
#pragma unroll
            for (int nt = 0; nt < 4; ++nt)
                acc[mt][nt] = __builtin_amdgcn_mfma_f32_16x16x32_bf16(af[mt], bf[nt], acc[mt][nt], 0, 0, 0);
    }

#pragma unroll
    for (int mt = 0; mt < 4; ++mt) {
#pragma unroll
        for (int nt = 0; nt < 4; ++nt) {
            const int ng = n0 + nbL + nt * 16 + lm;
            const float bv = bias[ng];
#pragma unroll
            for (int r = 0; r < 4; ++r) {
                const int m = m0 + mb + mt * 16 + q * 4 + r;   // m = b*512 + s
                const int s = m & 511, b = m >> 9;
                xu[(size_t)(s * 32 + b) * 4096 + ng] = f2bf(acc[mt][nt][r] + bv);
            }
        }
    }
}

// ---------------- phase 2: persistent recurrence ----------------
// Round-5 restructure — two coupled changes:
//  (a) FLAG-ARRAY barrier: the single fetch_add counter was a 64-way
//      same-address RMW -> ~2-3.5k cy serialization at the LLC atomic
//      unit per step. Now each WG stores its phase counter to its OWN
//      int (flags[nb], parallel stores, no RMW); every wave polls all
//      64 flags with ONE global_load_dword (lane i reads flags[i]) and
//      __all(v >= target). Observation = one LLC round trip.
//  (b) DUAL-STREAM pipeline: rows 0-15 and 16-31 are independent
//      recurrences. Phases alternate streams; stream-s sync/store
//      latency hides behind stream-(s^1) compute. Phase p (s=p&1,
//      t=p>>1) waits flags[*] >= p-1 (stores of phase p-2, same
//      stream, prev step). Max skew = 1 step/stream -> h double
//      buffer (parity per t) stays race-free.
// Ordering per phase: h-stores (sc1) -> per-wave vmcnt(0) ->
// __syncthreads (ALL waves drained) -> tid0 flag store -> out-stores
// (post-flag; drained overlapped by next phase's h-load waitcnt).

__global__ __launch_bounds__(256, 1) void lstm_rec(
    const u16* __restrict__ xu, const u16* __restrict__ Vp,
    const void* __restrict__ c0, u16* h_bf, void* outv, int* flags,
    const int* __restrict__ flag) {
    const int isbf = flag[0];
    const int nb = blockIdx.x;
    const int tid = threadIdx.x;
    const int w = tid >> 6;
    const int lane = tid & 63;
    const int lm = lane & 15;
    const int q = lane >> 4;

    // V gates 1..3: [g-1][ks][lane*8]  (1KB blocks, matches global_load_lds pattern)
    __shared__ __attribute__((aligned(16))) u16 Vl[3 * 32 * 512];     // 96 KiB
    __shared__ float part[4][4][16][18];   // [wave][gate][row][col] pad 18 -> 18 KiB

    const int em = tid >> 4;                   // row-in-stream 0..15
    const int en = tid & 15;
    const int ncol = nb * 16 + en;             // col within gate

    float cs0 = rd_f(c0, (size_t)em * H_ + ncol, isbf);          // stream 0: row em
    float cs1 = rd_f(c0, (size_t)(em + 16) * H_ + ncol, isbf);   // stream 1: row em+16

    float* outf = (float*)outv;
    u16*   outh = (u16*)outv;

    // ---- gate-0 V fragments in registers (32 VGPR, constant across steps) ----
    short8 bpre0[8];
#pragma unroll
    for (int kk = 0; kk < 8; ++kk) {
        const int ks = w * 8 + kk;
        bpre0[kk] = *(const short8*)(Vp + ((((size_t)0 * 64 + nb) * 32 + ks) * 64 + lane) * 8);
    }

    // ---- gates 1..3 V -> LDS once (96 blocks of 1KB; wave w takes b = w,w+4,..) ----
    for (int b = w; b < 96; b += 4) {
        const int gq = b >> 5;                 // 0..2 -> gate gq+1
        const int ks = b & 31;
        const u16* src = Vp + ((((size_t)(gq + 1) * 64 + nb) * 32 + ks) * 64 + lane) * 8;
        __builtin_amdgcn_global_load_lds((const __attribute__((address_space(1))) void*)src,
                                         (__attribute__((address_space(3))) void*)(Vl + b * 512),
                                         16, 0, 0);
    }
    __syncthreads();   // drains vmcnt: Vl ready

    float hlastf[2] = {0.f, 0.f};
    u16   hlastb[2] = {0, 0};

#pragma unroll 1
    for (int p = 0; p < 2 * S_; ++p) {
        const int s   = p & 1;
        const int t   = p >> 1;
        const int par = t & 1;

        // ---- 0) flag-array wait: every wave polls all 64 flags in one load ----
        if (p >= 2) {
            const int target = p - 1;
            while (true) {
                int v = __hip_atomic_load(&flags[lane], __ATOMIC_RELAXED, __HIP_MEMORY_SCOPE_AGENT);
                if (__all(v >= target)) break;
                __builtin_amdgcn_s_sleep(1);
            }
        }

        // ---- 1) batched h loads for this stream (8 x 16B, ONE wait) + xu ----
        const u16* hb = h_bf + par * (B_ * H_) + (s << 4) * H_;
        short8 ha[8];
#pragma unroll
        for (int kk = 0; kk < 8; ++kk) {
            const int ks = w * 8 + kk;
            ha[kk] = llc_load16(hb + lm * H_ + ks * 32 + q * 8);
        }
        u16 xv[4];
        {
            const u16* xt = xu + (size_t)t * (B_ * 4 * H_) + (size_t)(em + (s << 4)) * 4096;
#pragma unroll
            for (int g = 0; g < 4; ++g) xv[g] = xt[g * 1024 + ncol];
        }
        asm volatile("s_waitcnt vmcnt(0)" ::: "memory");
        __builtin_amdgcn_sched_barrier(0);

        // ---- 2) MFMA: gate0 from regs, gates1..3 from LDS (32 MFMA/wave) ----
        f32x4 acc[4] = {};
#pragma unroll
        for (int kk = 0; kk < 8; ++kk) {
            const int ks = w * 8 + kk;
            const short8 b1 = *(const short8*)(Vl + (0 * 32 + ks) * 512 + lane * 8);
            const short8 b2 = *(const short8*)(Vl + (1 * 32 + ks) * 512 + lane * 8);
            const short8 b3 = *(const short8*)(Vl + (2 * 32 + ks) * 512 + lane * 8);
            acc[0] = __builtin_amdgcn_mfma_f32_16x16x32_bf16(ha[kk], bpre0[kk], acc[0], 0, 0, 0);
            acc[1] = __builtin_amdgcn_mfma_f32_16x16x32_bf16(ha[kk], b1, acc[1], 0, 0, 0);
            acc[2] = __builtin_amdgcn_mfma_f32_16x16x32_bf16(ha[kk], b2, acc[2], 0, 0, 0);
            acc[3] = __builtin_amdgcn_mfma_f32_16x16x32_bf16(ha[kk], b3, acc[3], 0, 0, 0);
        }

        // ---- 3) partials -> LDS, cross-wave reduce, elementwise ----
#pragma unroll
        for (int g = 0; g < 4; ++g)
#pragma unroll
            for (int r = 0; r < 4; ++r)
                part[w][g][q * 4 + r][lm] = acc[g][r];
        __syncthreads();

        float z[4];
#pragma unroll
        for (int g = 0; g < 4; ++g)
            z[g] = zclamp(bf2f(xv[g]) + part[0][g][em][en] + part[1][g][em][en]
                                      + part[2][g][em][en] + part[3][g][em][en]);

        const float iv = sigm(z[0]), fv = sigm(z[1]), gv = tanh_(z[2]), ov = sigm(z[3]);
        float c = fv * (s ? cs1 : cs0) + iv * gv;
        if (s) cs1 = c; else cs0 = c;
        const float h = ov * tanh_(c);
        const u16 h16 = f2bf(h);
        hlastf[s] = h; hlastb[s] = h16;

        // ---- 4) h-store (sc1) -> drain -> all-wave rendezvous -> flag ----
        const int row = em + (s << 4);
        u16* hn = h_bf + (par ^ 1) * (B_ * H_);
        __hip_atomic_store(&hn[row * H_ + ncol], h16, __ATOMIC_RELAXED, __HIP_MEMORY_SCOPE_AGENT);
        asm volatile("s_waitcnt vmcnt(0)" ::: "memory");
        __syncthreads();   // all 4 waves' h-stores acked before flag release
        if (tid == 0)
            __hip_atomic_store(&flags[nb], p + 1, __ATOMIC_RELAXED, __HIP_MEMORY_SCOPE_AGENT);

        // ---- 5) out-store for (row, t): post-flag, off the critical path ----
        const size_t o = ((size_t)row * S_ + t) * H_ + ncol;
        if (isbf) outh[o] = h16; else outf[o] = h;
    }

    // ---- epilogue: final h/c ----
    {
        const size_t HS = (size_t)B_ * S_ * H_;
        const size_t h0_i = HS + (size_t)em * H_ + ncol;
        const size_t h1_i = HS + (size_t)(em + 16) * H_ + ncol;
        const size_t c0_i = HS + (size_t)B_ * H_ + (size_t)em * H_ + ncol;
        const size_t c1_i = HS + (size_t)B_ * H_ + (size_t)(em + 16) * H_ + ncol;
        if (isbf) {
            outh[h0_i] = hlastb[0]; outh[h1_i] = hlastb[1];
            outh[c0_i] = f2bf(cs0); outh[c1_i] = f2bf(cs1);
        } else {
            outf[h0_i] = hlastf[0]; outf[h1_i] = hlastf[1];
            outf[c0_i] = cs0;       outf[c1_i] = cs1;
        }
    }
}

// ---------------- host ----------------

extern "C" void kernel_launch(void* const* d_in, const int* in_sizes, int n_in,
                              void* d_out, int out_size, void* d_ws, size_t ws_size,
                              hipStream_t stream) {
    (void)in_sizes; (void)n_in; (void)out_size;
    if (ws_size < WS_NEED) return;   // diagnostic: out stays 0 -> absmax ~0.89 signature
    const void* x  = d_in[0];
    const void* h0 = d_in[1];
    const void* c0 = d_in[2];
    const void* U0 = d_in[3],  *V0 = d_in[4],  *bb0 = d_in[5];
    const void* U1 = d_in[6],  *V1 = d_in[7],  *bb1 = d_in[8];
    const void* U2 = d_in[9],  *V2 = d_in[10], *bb2 = d_in[11];
    const void* U3 = d_in[12], *V3 = d_in[13], *bb3 = d_in[14];

    char* ws = (char*)d_ws;
    int*   flags = (int*)(ws + OFF_BAR);     // 64 ints, one per WG
    int*   dflg  = (int*)(ws + OFF_DFLG);    // dtype flag
    u16*   hbf   = (u16*)(ws + OFF_HBF);
    float* bias  = (float*)(ws + OFF_BIAS);
    u16*   Ut    = (u16*)(ws + OFF_UT);
    u16*   Vp    = (u16*)(ws + OFF_VP);
    u16*   xu    = (u16*)(ws + OFF_XU);

    hipMemsetAsync(flags, 0, 256, stream);
    prep_probe<<<dim3(1), dim3(64), 0, stream>>>(x, dflg);
    prep_misc<<<dim3(144), dim3(256), 0, stream>>>(bb0, bb1, bb2, bb3, bias, h0, hbf, dflg);
    prep_ut<<<dim3(2048), dim3(256), 0, stream>>>(U0, U1, U2, U3, Ut, dflg);
    prep_vp<<<dim3(2048), dim3(256), 0, stream>>>(V0, V1, V2, V3, Vp, dflg);
    gemm_xu<<<dim3(4096), dim3(256), 0, stream>>>(x, Ut, bias, xu, dflg);
    lstm_rec<<<dim3(NBLK), dim3(256), 0, stream>>>(xu, Vp, c0, hbf, (void*)d_out, flags, dflg);
}

// Round 6
// 2990.292 us; speedup vs baseline: 1.3107x; 1.3107x over previous
//
#include <hip/hip_runtime.h>
#include <stdint.h>

typedef unsigned short u16;
typedef unsigned long long u64;
typedef __attribute__((ext_vector_type(8))) short short8;
typedef __attribute__((ext_vector_type(4))) float f32x4;
typedef __attribute__((ext_vector_type(4))) unsigned int u32x4;

#define B_ 32
#define S_ 512
#define H_ 1024
#define NBLK 64   // recurrence workgroups (<=256 CUs -> co-resident, spin barrier safe)

// ---- workspace layout (bytes) ----
// flags: 64 ints at 64B stride (spread over 32 x 128B lines) -> 8KB region.
static const size_t OFF_FLG  = 0;                         // flags[64] @ stride 16 ints
static const size_t OFF_HBF  = 8192;                      // h double buffer: 2*32*1024*2
static const size_t OFF_DFLG = OFF_HBF + 131072;          // dtype flag (256B pad)
static const size_t OFF_BIAS = OFF_HBF + 131072 + 256;    // fp32[4096]
static const size_t OFF_UT   = OFF_BIAS + 16384;          // U^T bf16 [4096][1024]
static const size_t OFF_VP   = OFF_UT + 8388608;          // V fragment-permuted bf16
static const size_t OFF_XU   = OFF_VP + 8388608;          // xu bf16 [512][32][4096]
static const size_t WS_NEED  = OFF_XU + (size_t)S_ * B_ * 4 * H_ * 2;

__device__ inline float bf2f(u16 u) {
    union { unsigned i; float f; } v; v.i = ((unsigned)u) << 16; return v.f;
}
__device__ inline u16 f2bf(float f) {
    union { float f; unsigned i; } v; v.f = f;
    unsigned r = v.i + 0x7fffu + ((v.i >> 16) & 1u);   // RNE
    return (u16)(r >> 16);
}
__device__ inline float sigm(float x) { return 1.0f / (1.0f + __expf(-x)); }
__device__ inline float tanh_(float x) {
    x = fminf(fmaxf(x, -30.0f), 30.0f);
    float e = __expf(-2.0f * x);
    return (1.0f - e) / (1.0f + e);
}
// NaN-proof clamp: fmaxf/fminf drop a NaN operand -> result always finite.
__device__ inline float zclamp(float x) { return fminf(fmaxf(x, -60.0f), 60.0f); }

// dual-dtype element read -> bf16 bits
__device__ inline u16 rd_bf(const void* p, size_t idx, int isbf) {
    return isbf ? ((const u16*)p)[idx] : f2bf(((const float*)p)[idx]);
}
__device__ inline float rd_f(const void* p, size_t idx, int isbf) {
    return isbf ? bf2f(((const u16*)p)[idx]) : ((const float*)p)[idx];
}

// system-scope 16B load: bypass (possibly stale) per-CU L1 / per-XCD L2,
// served by the coherent memory-side Infinity Cache. Issues WITHOUT an
// implicit waitcnt -> caller batches N loads then waits ONCE.
__device__ inline short8 llc_load16(const u16* p) {
    u32x4 r;
    asm volatile("global_load_dwordx4 %0, %1, off sc0 sc1"
                 : "=&v"(r) : "v"(p));
    union { u32x4 u; short8 s; } cv; cv.u = r; return cv.s;
}

// ---------------- dtype probe ----------------
__global__ void prep_probe(const void* x, int* flag) {
    if (blockIdx.x == 0 && threadIdx.x == 0) {
        const u16* p = (const u16*)x;
        int bfish = 0;
        for (int i = 0; i < 512; i += 2) {
            int e = (p[i] >> 7) & 0xFF;
            if (e >= 118 && e <= 131) ++bfish;
        }
        flag[0] = (bfish >= 128) ? 1 : 0;   // 1 = bf16 buffers, 0 = fp32 buffers
    }
}

// ---------------- prep kernels ----------------

__global__ void prep_misc(const void* b0, const void* b1, const void* b2, const void* b3,
                          float* __restrict__ bias, const void* h0,
                          u16* __restrict__ hbf, const int* __restrict__ flag) {
    const int isbf = flag[0];
    int i = blockIdx.x * 256 + threadIdx.x;
    if (i < 4096) {
        int g = i >> 10, n = i & 1023;
        const void* bp = (g == 0) ? b0 : (g == 1) ? b1 : (g == 2) ? b2 : b3;
        bias[i] = rd_f(bp, n, isbf);
    }
    int j = i - 4096;
    if (j >= 0 && j < B_ * H_) hbf[j] = rd_bf(h0, j, isbf);
}

// Ut[(g*1024+n)*1024 + k] = U_g[k*1024 + n]
__global__ void prep_ut(const void* u0, const void* u1, const void* u2, const void* u3,
                        u16* __restrict__ Ut, const int* __restrict__ flag) {
    const int isbf = flag[0];
    int idx = blockIdx.x * 256 + threadIdx.x;          // [4][128][1024]
    int g  = idx >> 17;
    int k8 = (idx >> 10) & 127;
    int n  = idx & 1023;
    const void* Ug = (g == 0) ? u0 : (g == 1) ? u1 : (g == 2) ? u2 : u3;
    int k0 = k8 * 8;
    union { u16 a[8]; short8 v; } t;
#pragma unroll
    for (int j = 0; j < 8; ++j) t.a[j] = rd_bf(Ug, (size_t)(k0 + j) * 1024 + n, isbf);
    *(short8*)(Ut + ((size_t)(g * 1024 + n) * 1024 + k0)) = t.v;
}

// Vp[((g*64+nb)*32+ks)*64+lane][8] = V_g[k][n], n=nb*16+(lane&15), k=ks*32+(lane>>4)*8+j
__global__ void prep_vp(const void* v0, const void* v1, const void* v2, const void* v3,
                        u16* __restrict__ Vp, const int* __restrict__ flag) {
    const int isbf = flag[0];
    int idx = blockIdx.x * 256 + threadIdx.x;          // [4][64][32][64]
    int lane = idx & 63;
    int ks = (idx >> 6) & 31;
    int nb = (idx >> 11) & 63;
    int g  = idx >> 17;
    const void* Vg = (g == 0) ? v0 : (g == 1) ? v1 : (g == 2) ? v2 : v3;
    int n  = nb * 16 + (lane & 15);
    int kb = ks * 32 + (lane >> 4) * 8;
    union { u16 a[8]; short8 v; } t;
#pragma unroll
    for (int j = 0; j < 8; ++j) t.a[j] = rd_bf(Vg, (size_t)(kb + j) * 1024 + n, isbf);
    *(short8*)(Vp + (size_t)idx * 8) = t.v;
}

// ---------------- phase 1: xu = x @ U + b  (bf16 out, [s][b][4096]) ----------------

__global__ __launch_bounds__(256) void gemm_xu(
    const void* __restrict__ xv, const u16* __restrict__ Ut,
    const float* __restrict__ bias, u16* __restrict__ xu,
    const int* __restrict__ flag) {
    const int isbf = flag[0];
    const int bx = blockIdx.x;
    const int m0 = (bx & 127) * 128;
    const int n0 = (bx >> 7) * 128;
    const int tid = threadIdx.x;
    const int w = tid >> 6, lane = tid & 63;
    const int lm = lane & 15, q = lane >> 4;
    const int r4 = lane >> 2, c4 = lane & 3;

    __shared__ __attribute__((aligned(16))) u16 As[128 * 32];
    __shared__ __attribute__((aligned(16))) u16 Bs[128 * 32];

    const int mb = (w >> 1) * 64, nbL = (w & 1) * 64;
    f32x4 acc[4][4] = {};

    for (int k0 = 0; k0 < 1024; k0 += 32) {
        __syncthreads();
#pragma unroll
        for (int i2 = 0; i2 < 2; ++i2) {
            const int i = w * 2 + i2;
            const size_t aoff = (size_t)(m0 + i * 16 + r4) * 1024 + k0 + c4 * 8;
            if (isbf) {
                const u16* ga = (const u16*)xv + aoff;
                __builtin_amdgcn_global_load_lds((const __attribute__((address_space(1))) void*)ga,
                                                 (__attribute__((address_space(3))) void*)(As + i * 512),
                                                 16, 0, 0);
            } else {
                const float* ga = (const float*)xv + aoff;
                f32x4 f0 = *(const f32x4*)ga;
                f32x4 f1 = *(const f32x4*)(ga + 4);
                union { u16 a[8]; short8 v; } t;
#pragma unroll
                for (int j = 0; j < 4; ++j) { t.a[j] = f2bf(f0[j]); t.a[4 + j] = f2bf(f1[j]); }
                *(short8*)(As + i * 512 + lane * 8) = t.v;
            }
            const u16* gb = Ut + (size_t)(n0 + i * 16 + r4) * 1024 + k0 + c4 * 8;
            __builtin_amdgcn_global_load_lds((const __attribute__((address_space(1))) void*)gb,
                                             (__attribute__((address_space(3))) void*)(Bs + i * 512),
                                             16, 0, 0);
        }
        __syncthreads();

        short8 af[4], bf[4];
#pragma unroll
        for (int mt = 0; mt < 4; ++mt)
            af[mt] = *(const short8*)(As + (mb + mt * 16 + lm) * 32 + q * 8);
#pragma unroll
        for (int nt = 0; nt < 4; ++nt)
            bf[nt] = *(const short8*)(Bs + (nbL + nt * 16 + lm) * 32 + q * 8);
#pragma unroll
        for (int mt = 0; mt < 4; ++mt)
#pragma unroll
            for (int nt = 0; nt < 4; ++nt)
                acc[mt][nt] = __builtin_amdgcn_mfma_f32_16x16x32_bf16(af[mt], bf[nt], acc[mt][nt], 0, 0, 0);
    }

#pragma unroll
    for (int mt = 0; mt < 4; ++mt) {
#pragma unroll
        for (int nt = 0; nt < 4; ++nt) {
            const int ng = n0 + nbL + nt * 16 + lm;
            const float bv = bias[ng];
#pragma unroll
            for (int r = 0; r < 4; ++r) {
                const int m = m0 + mb + mt * 16 + q * 4 + r;   // m = b*512 + s
                const int s = m & 511, b = m >> 9;
                xu[(size_t)(s * 32 + b) * 4096 + ng] = f2bf(acc[mt][nt][r] + bv);
            }
        }
    }
}

// ---------------- phase 2: persistent recurrence ----------------
// Round-6: round-4 full-step structure (one grid sync per step, 64
// MFMA/wave) + flag-array barrier ONLY (single-variable change).
// R4/R5 two-point experiment: barrier round trip ~6.5-9.7k cy dominates
// the 12.7k cy step; halving work per barrier (R5) regressed because
// sync >> compute/2. Fix the barrier itself:
//  * flags[64] at 64B stride (32 cache lines) -> 64 parallel stores, no
//    same-line serialization (R5 packed them in 2 lines; R4 was a 64-way
//    same-address RMW).
//  * all-wave poll: lane i loads flags[i*16], __all(v>=t+1); no s_sleep,
//    no post-poll syncthreads (each wave proceeds on observation).
//  * loads for step t (h sc0sc1 + xu) issue together at loop top, ONE
//    vmcnt(0); out-stores issue with h-stores -> the single pre-flag
//    drain covers all acks in parallel (xu prefetch no longer sits in
//    the pre-flag drain as in R4).
// Ordering: h/out-stores -> vmcnt(0) (per wave) -> __syncthreads (all
// waves acked) -> tid0 flag store. Reader: poll sees flag -> its h-loads
// (sc0 sc1, LLC) are issued after -> no stale data possible.

__global__ __launch_bounds__(256, 1) void lstm_rec(
    const u16* __restrict__ xu, const u16* __restrict__ Vp,
    const void* __restrict__ c0, u16* h_bf, void* outv, int* flags,
    const int* __restrict__ flag) {
    const int isbf = flag[0];
    const int nb = blockIdx.x;
    const int tid = threadIdx.x;
    const int w = tid >> 6;
    const int lane = tid & 63;
    const int lm = lane & 15;
    const int q = lane >> 4;

    // V gates 1..3: [g-1][ks][lane*8]  (1KB blocks, matches global_load_lds pattern)
    __shared__ __attribute__((aligned(16))) u16 Vl[3 * 32 * 512];     // 96 KiB
    __shared__ float part[4][4][2][16][18];   // [wave][gate][mt][row][col] pad 18

    const int em = tid >> 4;                   // batch row 0..15
    const int en = tid & 15;
    const int ncol = nb * 16 + en;             // col within gate

    float c_a = rd_f(c0, (size_t)em * H_ + ncol, isbf);
    float c_b = rd_f(c0, (size_t)(em + 16) * H_ + ncol, isbf);

    float* outf = (float*)outv;
    u16*   outh = (u16*)outv;

    // ---- gate-0 V fragments in registers (32 VGPR, constant across steps) ----
    short8 bpre0[8];
#pragma unroll
    for (int kk = 0; kk < 8; ++kk) {
        const int ks = w * 8 + kk;
        bpre0[kk] = *(const short8*)(Vp + ((((size_t)0 * 64 + nb) * 32 + ks) * 64 + lane) * 8);
    }

    // ---- gates 1..3 V -> LDS once (96 blocks of 1KB; wave w takes b = w,w+4,..) ----
    for (int b = w; b < 96; b += 4) {
        const int gq = b >> 5;                 // 0..2 -> gate gq+1
        const int ks = b & 31;
        const u16* src = Vp + ((((size_t)(gq + 1) * 64 + nb) * 32 + ks) * 64 + lane) * 8;
        __builtin_amdgcn_global_load_lds((const __attribute__((address_space(1))) void*)src,
                                         (__attribute__((address_space(3))) void*)(Vl + b * 512),
                                         16, 0, 0);
    }
    __syncthreads();   // drains vmcnt: Vl ready

    float hA = 0.f, hB = 0.f;
    u16 hAb = 0, hBb = 0;

#pragma unroll 1
    for (int t = 0; t < S_; ++t) {
        const int par = t & 1;

        // ---- 0) flag-array wait: all waves poll 64 spread flags, one load ----
        if (t) {
            while (true) {
                int v = __hip_atomic_load(&flags[lane * 16], __ATOMIC_RELAXED, __HIP_MEMORY_SCOPE_AGENT);
                if (__all(v >= t)) break;
            }
        }

        // ---- 1) batched loads for step t: 16 x 16B h (sc0sc1) + 8 xu, ONE wait ----
        const u16* hb = h_bf + par * (B_ * H_);
        short8 ha[8], hbv[8];
#pragma unroll
        for (int kk = 0; kk < 8; ++kk) {
            const int ks = w * 8 + kk;
            ha[kk]  = llc_load16(hb + lm * H_ + ks * 32 + q * 8);
            hbv[kk] = llc_load16(hb + (lm + 16) * H_ + ks * 32 + q * 8);
        }
        u16 xva[4], xvb[4];
        {
            const u16* xt = xu + (size_t)t * (B_ * 4 * H_);
#pragma unroll
            for (int g = 0; g < 4; ++g) {
                xva[g] = xt[em * 4096 + g * 1024 + ncol];
                xvb[g] = xt[(em + 16) * 4096 + g * 1024 + ncol];
            }
        }
        asm volatile("s_waitcnt vmcnt(0)" ::: "memory");
        __builtin_amdgcn_sched_barrier(0);

        // ---- 2) MFMA phase: gate0 from regs, gates1..3 from LDS ----
        f32x4 acc[4][2] = {};
#pragma unroll
        for (int kk = 0; kk < 8; ++kk) {
            const int ks = w * 8 + kk;
            const short8 b1 = *(const short8*)(Vl + (0 * 32 + ks) * 512 + lane * 8);
            const short8 b2 = *(const short8*)(Vl + (1 * 32 + ks) * 512 + lane * 8);
            const short8 b3 = *(const short8*)(Vl + (2 * 32 + ks) * 512 + lane * 8);
            acc[0][0] = __builtin_amdgcn_mfma_f32_16x16x32_bf16(ha[kk],  bpre0[kk], acc[0][0], 0, 0, 0);
            acc[0][1] = __builtin_amdgcn_mfma_f32_16x16x32_bf16(hbv[kk], bpre0[kk], acc[0][1], 0, 0, 0);
            acc[1][0] = __builtin_amdgcn_mfma_f32_16x16x32_bf16(ha[kk],  b1, acc[1][0], 0, 0, 0);
            acc[1][1] = __builtin_amdgcn_mfma_f32_16x16x32_bf16(hbv[kk], b1, acc[1][1], 0, 0, 0);
            acc[2][0] = __builtin_amdgcn_mfma_f32_16x16x32_bf16(ha[kk],  b2, acc[2][0], 0, 0, 0);
            acc[2][1] = __builtin_amdgcn_mfma_f32_16x16x32_bf16(hbv[kk], b2, acc[2][1], 0, 0, 0);
            acc[3][0] = __builtin_amdgcn_mfma_f32_16x16x32_bf16(ha[kk],  b3, acc[3][0], 0, 0, 0);
            acc[3][1] = __builtin_amdgcn_mfma_f32_16x16x32_bf16(hbv[kk], b3, acc[3][1], 0, 0, 0);
        }

        // ---- 3) partials -> LDS, cross-wave reduce, elementwise ----
#pragma unroll
        for (int g = 0; g < 4; ++g)
#pragma unroll
            for (int mt = 0; mt < 2; ++mt)
#pragma unroll
                for (int r = 0; r < 4; ++r)
                    part[w][g][mt][q * 4 + r][lm] = acc[g][mt][r];
        __syncthreads();

        float z_a[4], z_b[4];
#pragma unroll
        for (int g = 0; g < 4; ++g) {
            z_a[g] = zclamp(bf2f(xva[g]) + part[0][g][0][em][en] + part[1][g][0][em][en]
                                         + part[2][g][0][em][en] + part[3][g][0][em][en]);
            z_b[g] = zclamp(bf2f(xvb[g]) + part[0][g][1][em][en] + part[1][g][1][em][en]
                                         + part[2][g][1][em][en] + part[3][g][1][em][en]);
        }

        float ia = sigm(z_a[0]), fa = sigm(z_a[1]), ga = tanh_(z_a[2]), oa = sigm(z_a[3]);
        c_a = fa * c_a + ia * ga;
        hA = oa * tanh_(c_a);
        float ib = sigm(z_b[0]), fb = sigm(z_b[1]), gb = tanh_(z_b[2]), ob = sigm(z_b[3]);
        c_b = fb * c_b + ib * gb;
        hB = ob * tanh_(c_b);

        hAb = f2bf(hA); hBb = f2bf(hB);

        // ---- 4) h-stores + out-stores: one parallel drain ----
        u16* hn = h_bf + (par ^ 1) * (B_ * H_);
        __hip_atomic_store(&hn[em * H_ + ncol],        hAb, __ATOMIC_RELAXED, __HIP_MEMORY_SCOPE_AGENT);
        __hip_atomic_store(&hn[(em + 16) * H_ + ncol], hBb, __ATOMIC_RELAXED, __HIP_MEMORY_SCOPE_AGENT);

        const size_t oA = ((size_t)em * S_ + t) * H_ + ncol;
        const size_t oB = ((size_t)(em + 16) * S_ + t) * H_ + ncol;
        if (isbf) { outh[oA] = hAb; outh[oB] = hBb; }
        else      { outf[oA] = hA;  outf[oB] = hB;  }

        // ---- 5) drain -> all-wave rendezvous -> flag release ----
        asm volatile("s_waitcnt vmcnt(0)" ::: "memory");
        __syncthreads();   // all 4 waves' stores acked before flag release
        if (tid == 0)
            __hip_atomic_store(&flags[nb * 16], t + 1, __ATOMIC_RELAXED, __HIP_MEMORY_SCOPE_AGENT);
    }

    // ---- epilogue: final h/c ----
    {
        const size_t HS = (size_t)B_ * S_ * H_;
        const size_t hA_i = HS + (size_t)em * H_ + ncol;
        const size_t hB_i = HS + (size_t)(em + 16) * H_ + ncol;
        const size_t cA_i = HS + (size_t)B_ * H_ + (size_t)em * H_ + ncol;
        const size_t cB_i = HS + (size_t)B_ * H_ + (size_t)(em + 16) * H_ + ncol;
        if (isbf) {
            outh[hA_i] = hAb; outh[hB_i] = hBb;
            outh[cA_i] = f2bf(c_a); outh[cB_i] = f2bf(c_b);
        } else {
            outf[hA_i] = hA; outf[hB_i] = hB;
            outf[cA_i] = c_a; outf[cB_i] = c_b;
        }
    }
}

// ---------------- host ----------------

extern "C" void kernel_launch(void* const* d_in, const int* in_sizes, int n_in,
                              void* d_out, int out_size, void* d_ws, size_t ws_size,
                              hipStream_t stream) {
    (void)in_sizes; (void)n_in; (void)out_size;
    if (ws_size < WS_NEED) return;   // diagnostic: out stays 0 -> absmax ~0.89 signature
    const void* x  = d_in[0];
    const void* h0 = d_in[1];
    const void* c0 = d_in[2];
    const void* U0 = d_in[3],  *V0 = d_in[4],  *bb0 = d_in[5];
    const void* U1 = d_in[6],  *V1 = d_in[7],  *bb1 = d_in[8];
    const void* U2 = d_in[9],  *V2 = d_in[10], *bb2 = d_in[11];
    const void* U3 = d_in[12], *V3 = d_in[13], *bb3 = d_in[14];

    char* ws = (char*)d_ws;
    int*   flags = (int*)(ws + OFF_FLG);     // 64 flags @ 64B stride
    int*   dflg  = (int*)(ws + OFF_DFLG);    // dtype flag
    u16*   hbf   = (u16*)(ws + OFF_HBF);
    float* bias  = (float*)(ws + OFF_BIAS);
    u16*   Ut    = (u16*)(ws + OFF_UT);
    u16*   Vp    = (u16*)(ws + OFF_VP);
    u16*   xu    = (u16*)(ws + OFF_XU);

    hipMemsetAsync(flags, 0, 8192, stream);
    prep_probe<<<dim3(1), dim3(64), 0, stream>>>(x, dflg);
    prep_misc<<<dim3(144), dim3(256), 0, stream>>>(bb0, bb1, bb2, bb3, bias, h0, hbf, dflg);
    prep_ut<<<dim3(2048), dim3(256), 0, stream>>>(U0, U1, U2, U3, Ut, dflg);
    prep_vp<<<dim3(2048), dim3(256), 0, stream>>>(V0, V1, V2, V3, Vp, dflg);
    gemm_xu<<<dim3(4096), dim3(256), 0, stream>>>(x, Ut, bias, xu, dflg);
    lstm_rec<<<dim3(NBLK), dim3(256), 0, stream>>>(xu, Vp, c0, hbf, (void*)d_out, flags, dflg);
}